// Round 17
// baseline (199.897 us; speedup 1.0000x reference)
//
#include <hip/hip_runtime.h>
#include <hip/hip_bf16.h>

using f16x8 = __attribute__((ext_vector_type(8))) _Float16;  // 8 fp16 (4 VGPRs)
using f32x4 = __attribute__((ext_vector_type(4))) float;
using u16 = unsigned short;
using u64 = unsigned long long;

__device__ __forceinline__ u16 f2h(float v) {
    _Float16 h = (_Float16)v;
    u16 r; __builtin_memcpy(&r, &h, 2); return r;
}
__device__ __forceinline__ float h2f(u16 x) {
    _Float16 h; __builtin_memcpy(&h, &x, 2); return (float)h;
}

// bank-decorrelation XOR: chunk permutation within a row's 4x16B chunks
__device__ __forceinline__ int fsw(int row) { return (row & 3) ^ ((row >> 2) & 3); }
__device__ __forceinline__ int aoff(int row, int kq) {
    return row * 32 + ((kq ^ fsw(row)) * 8);
}

// async global->LDS DMA, 16B per lane; LDS dest = wave-uniform base + lane*16
__device__ __forceinline__ void gl16(const u16* g, const u16* l) {
    __builtin_amdgcn_global_load_lds(
        (const __attribute__((address_space(1))) unsigned int*)g,
        (__attribute__((address_space(3))) unsigned int*)l, 16, 0, 0);
}

// ---------------------------------------------------------------------------
// fp16 MFMA GEMM (fp32 accumulate): tile 128 rows x 256 cols, BK=32.
// 512 threads = 8 waves (2x4); each wave owns a 64x64 output tile.
// launch_bounds(512,4): 4 waves/SIMD; (512,6) would force <=85 unified
// VGPR+AGPR/wave and spill the 64-AGPR accumulator (round-10: 155 MB spill).
// C-writes are nontemporal: consumed by a LATER kernel (cross-XCD L2s are
// private, so caching own output only evicts useful lines).
// ---------------------------------------------------------------------------
template<int ACT>
__global__ __launch_bounds__(512, 4)
void mfma_k(const u16* __restrict__ A, int lda,
            const u16* __restrict__ BT,
            const float* __restrict__ bias,
            u16* __restrict__ Ch,
            int ldc, int M, int K) {
    __shared__ u16 As[2][128 * 32];   // 8 KB x2
    __shared__ u16 Bs[2][256 * 32];   // 16 KB x2

    const int tid  = threadIdx.x;
    const int brow = blockIdx.x * 128;
    const int lane = tid & 63;
    const int w    = tid >> 6;
    const int wr = w >> 2, wc = w & 3;
    const int lr = lane & 15, lq = lane >> 4;

    const int rsub = lane >> 2;
    const int s    = lane & 3;
    const int rowA  = w * 16 + rsub;
    const int rowB0 = w * 16 + rsub;
    const int rowB1 = 128 + w * 16 + rsub;
    const u16* gA  = A  + (size_t)(brow + rowA) * lda + (s ^ fsw(rowA))  * 8;
    const u16* gB0 = BT + (size_t)rowB0        * K   + (s ^ fsw(rowB0)) * 8;
    const u16* gB1 = BT + (size_t)rowB1        * K   + (s ^ fsw(rowB1)) * 8;

    f32x4 acc[4][4] = {};

#define STAGE(buf, koff)                                                       \
    do {                                                                       \
        gl16(gA  + (koff), &As[buf][w * 512]);                                 \
        gl16(gB0 + (koff), &Bs[buf][w * 512]);                                 \
        gl16(gB1 + (koff), &Bs[buf][(8 + w) * 512]);                           \
    } while (0)

    STAGE(0, 0);
    __syncthreads();

    const int nt = K >> 5;
    int cur = 0;
    for (int t = 0; t < nt; ++t) {
        if (t + 1 < nt) STAGE(cur ^ 1, (t + 1) * 32);

        f16x8 bf[4];
        #pragma unroll
        for (int n = 0; n < 4; ++n)
            bf[n] = *reinterpret_cast<const f16x8*>(&Bs[cur][aoff(wc * 64 + n * 16 + lr, lq)]);
        #pragma unroll
        for (int m = 0; m < 4; ++m) {
            f16x8 af = *reinterpret_cast<const f16x8*>(&As[cur][aoff(wr * 64 + m * 16 + lr, lq)]);
            #pragma unroll
            for (int n = 0; n < 4; ++n)
                acc[m][n] = __builtin_amdgcn_mfma_f32_16x16x32_f16(af, bf[n], acc[m][n], 0, 0, 0);
        }

        if (t + 1 < nt) {
            __syncthreads();
            cur ^= 1;
        }
    }
#undef STAGE

    // epilogue: frag layout col=lane&15, row=(lane>>4)*4+r (m89-verified)
    #pragma unroll
    for (int m = 0; m < 4; ++m) {
        #pragma unroll
        for (int n = 0; n < 4; ++n) {
            #pragma unroll
            for (int r = 0; r < 4; ++r) {
                int grow = brow + wr * 64 + m * 16 + lq * 4 + r;
                if (grow >= M) continue;
                int gcol = wc * 64 + n * 16 + lr;
                float v = acc[m][n][r] + bias[gcol];
                if (ACT == 1) v = fmaxf(v, 0.f);
                __builtin_nontemporal_store(f2h(v), &Ch[(size_t)grow * ldc + gcol]);
            }
        }
    }
}

// ---------------------------------------------------------------------------
// Fused z+output kernel: z = relu([t0|agg] @ zWT + bzc)   (tile 128x256, K=512)
// then out = tanh(z @ p2 + b2) in-kernel via z->LDS (aliased over staging pool)
// and two 128-col MFMA phases. z never touches HBM.
// ---------------------------------------------------------------------------
__global__ __launch_bounds__(512, 4)
void mfmaz_k(const u16* __restrict__ A, int lda,
             const u16* __restrict__ BT,
             const float* __restrict__ bias,
             const u16* __restrict__ P2T, const float* __restrict__ b2,
             float* __restrict__ out, int M, int K) {
    __shared__ u16 pool[2 * 128 * 32 + 2 * 256 * 32];   // 48 KB
    u16 (*As)[128 * 32] = reinterpret_cast<u16(*)[128 * 32]>(pool);
    u16 (*Bs)[256 * 32] = reinterpret_cast<u16(*)[256 * 32]>(pool + 2 * 128 * 32);
    u16 (*zs)[136]      = reinterpret_cast<u16(*)[136]>(pool);  // 128 x 136 = 34 KB

    const int tid  = threadIdx.x;
    const int brow = blockIdx.x * 128;
    const int lane = tid & 63;
    const int w    = tid >> 6;
    const int wr = w >> 2, wc = w & 3;
    const int lr = lane & 15, lq = lane >> 4;

    const int rsub = lane >> 2;
    const int s    = lane & 3;
    const int rowA  = w * 16 + rsub;
    const int rowB0 = w * 16 + rsub;
    const int rowB1 = 128 + w * 16 + rsub;
    const u16* gA  = A  + (size_t)(brow + rowA) * lda + (s ^ fsw(rowA))  * 8;
    const u16* gB0 = BT + (size_t)rowB0        * K   + (s ^ fsw(rowB0)) * 8;
    const u16* gB1 = BT + (size_t)rowB1        * K   + (s ^ fsw(rowB1)) * 8;

    f32x4 acc[4][4] = {};

#define STAGE(buf, koff)                                                       \
    do {                                                                       \
        gl16(gA  + (koff), &As[buf][w * 512]);                                 \
        gl16(gB0 + (koff), &Bs[buf][w * 512]);                                 \
        gl16(gB1 + (koff), &Bs[buf][(8 + w) * 512]);                           \
    } while (0)

    STAGE(0, 0);
    __syncthreads();

    const int nt = K >> 5;
    int cur = 0;
    for (int t = 0; t < nt; ++t) {
        if (t + 1 < nt) STAGE(cur ^ 1, (t + 1) * 32);

        f16x8 bf[4];
        #pragma unroll
        for (int n = 0; n < 4; ++n)
            bf[n] = *reinterpret_cast<const f16x8*>(&Bs[cur][aoff(wc * 64 + n * 16 + lr, lq)]);
        #pragma unroll
        for (int m = 0; m < 4; ++m) {
            f16x8 af = *reinterpret_cast<const f16x8*>(&As[cur][aoff(wr * 64 + m * 16 + lr, lq)]);
            #pragma unroll
            for (int n = 0; n < 4; ++n)
                acc[m][n] = __builtin_amdgcn_mfma_f32_16x16x32_f16(af, bf[n], acc[m][n], 0, 0, 0);
        }

        if (t + 1 < nt) {
            __syncthreads();
            cur ^= 1;
        }
    }
#undef STAGE

    __syncthreads();   // all As/Bs reads done; pool may be reused as zs

    // two phases over z columns: phase p covers z cols [128p, 128p+128)
    f32x4 acc2 = {};
    #pragma unroll
    for (int p = 0; p < 2; ++p) {
        if ((wc >> 1) == p) {
            const int colp = (wc & 1) * 64;
            #pragma unroll
            for (int m = 0; m < 4; ++m) {
                #pragma unroll
                for (int n = 0; n < 4; ++n) {
                    #pragma unroll
                    for (int r = 0; r < 4; ++r) {
                        int row  = wr * 64 + m * 16 + lq * 4 + r;
                        int gcol = wc * 64 + n * 16 + lr;
                        float v = fmaxf(acc[m][n][r] + bias[gcol], 0.f);
                        zs[row][colp + n * 16 + lr] = f2h(v);
                    }
                }
            }
        }
        __syncthreads();
        #pragma unroll
        for (int ks = 0; ks < 4; ++ks) {
            f16x8 af = *reinterpret_cast<const f16x8*>(&zs[w * 16 + lr][ks * 32 + lq * 8]);
            f16x8 bf = *reinterpret_cast<const f16x8*>(P2T + lr * 256 + p * 128 + ks * 32 + lq * 8);
            acc2 = __builtin_amdgcn_mfma_f32_16x16x32_f16(af, bf, acc2, 0, 0, 0);
        }
        __syncthreads();
    }

    const float b = b2[lr];
    #pragma unroll
    for (int r = 0; r < 4; ++r) {
        int grow = brow + w * 16 + lq * 4 + r;
        if (grow < M) __builtin_nontemporal_store(tanhf(acc2[r] + b), &out[(size_t)grow * 16 + lr]);
    }
}

// ---------------------------------------------------------------------------
// Fused setup (one launch) — exact round-14 structure:
//   blocks [0,257)            : wcT = (W2@Wc)^T fp16 (+ bias row -> btc)
//   blocks [257,514)          : zWT[:, :256] = (W2@P1h)^T fp16 (+ bias -> bzc)
//   blocks [514,770)          : zWT[:, 256:] = P1a^T fp16
//   blocks [770,786)          : p2T = post_w2^T fp16
//   blocks [786, 786+nsb)     : counts[i] = 0
//   blocks [786+nsb, ...)     : pre-MLP layer 1 (16 rows/block) -> hcat
// (r15 lesson: hist's atomics fused here cost +30 us — hist stays standalone.)
// ---------------------------------------------------------------------------
__global__ __launch_bounds__(256)
void setup_k(const float* __restrict__ pre_w2, const float* __restrict__ pre_b2,
             const float* __restrict__ conv_w, const float* __restrict__ conv_b,
             const float* __restrict__ post_w1, const float* __restrict__ post_b1,
             const float* __restrict__ post_w2,
             const float* __restrict__ x, const float* __restrict__ pre_w1,
             const float* __restrict__ pre_b1,
             u16* __restrict__ wcT, float* __restrict__ btc,
             u16* __restrict__ zWT, float* __restrict__ bzc,
             u16* __restrict__ p2T, int* __restrict__ counts,
             u16* __restrict__ t0, int nsb, int N) {
    const int b = blockIdx.x;
    const int n = threadIdx.x;
    if (b < 514) {
        const bool second = (b >= 257);
        const int k = second ? (b - 257) : b;
        const float* B    = second ? post_w1 : conv_w;
        const float* addv = second ? post_b1 : conv_b;
        u16*  WT   = second ? zWT : wcT;
        float* bo  = second ? bzc : btc;
        const int ldout = second ? 512 : 256;
        __shared__ float a_sh[256];
        const bool isBias = (k == 256);
        a_sh[n] = isBias ? pre_b2[n] : pre_w2[(size_t)k * 256 + n];
        __syncthreads();
        float s = 0.f;
        #pragma unroll 8
        for (int j = 0; j < 256; ++j)
            s = fmaf(a_sh[j], B[(size_t)j * 256 + n], s);
        if (isBias) bo[n] = s + addv[n];
        else        WT[(size_t)n * ldout + k] = f2h(s);
    } else if (b < 770) {
        const int j = b - 514;
        zWT[(size_t)j * 512 + 256 + n] = f2h(post_w1[(size_t)(256 + n) * 256 + j]);
    } else if (b < 786) {
        const int j = b - 770;
        p2T[(size_t)j * 256 + n] = f2h(post_w2[(size_t)n * 16 + j]);
    } else if (b < 786 + nsb) {
        const int i = (b - 786) * 256 + n;
        if (i < N) counts[i] = 0;
    } else {
        // pre-MLP layer 1, 16 rows per block (round-14 proven form)
        __shared__ float ws[16 * 256];
        __shared__ float xs[16][17];
        const int r0 = (b - 786 - nsb) * 16;
        for (int i = n; i < 16 * 256; i += 256) ws[i] = pre_w1[i];
        {
            int rr = n >> 4, cc = n & 15;
            xs[rr][cc] = (r0 + rr < N) ? x[(size_t)(r0 + rr) * 16 + cc] : 0.f;
        }
        __syncthreads();
        const float bb = pre_b1[n];
        for (int r = 0; r < 16; r++) {
            if (r0 + r >= N) break;
            float acc = bb;
            #pragma unroll
            for (int k = 0; k < 16; k++) acc = fmaf(xs[r][k], ws[k * 256 + n], acc);
            __builtin_nontemporal_store(f2h(fmaxf(acc, 0.f)), &t0[(size_t)(r0 + r) * 512 + n]);
        }
    }
}

// ---------------------------------------------------------------------------
// CSR-by-destination build (rank trick: no atomics in fill)
// ---------------------------------------------------------------------------
__global__ void hist_k(const int* __restrict__ dst, int E,
                       int* __restrict__ counts, int* __restrict__ rank) {
    int i = blockIdx.x * blockDim.x + threadIdx.x;
    if (i < E) {
        int r = atomicAdd(&counts[dst[i]], 1);
        __builtin_nontemporal_store(r, &rank[i]);
    }
}

__global__ __launch_bounds__(256)
void scan1_k(const int* __restrict__ counts, int* __restrict__ pre,
             int* __restrict__ bsum, int n) {
    __shared__ int sh[256];
    const int t = threadIdx.x;
    const int i = blockIdx.x * 256 + t;
    int v = (i < n) ? counts[i] : 0;
    sh[t] = v;
    __syncthreads();
    #pragma unroll
    for (int d = 1; d < 256; d <<= 1) {
        int x = (t >= d) ? sh[t - d] : 0;
        __syncthreads();
        sh[t] += x;
        __syncthreads();
    }
    if (i < n) pre[i] = sh[t] - v;
    if (t == 255) bsum[blockIdx.x] = sh[255];
}

// stage 2+3 fused: each block computes its offset = sum(bsum[0..bid)) inline
__global__ __launch_bounds__(256)
void scan3_k(const int* __restrict__ pre, const int* __restrict__ bsum,
             int* __restrict__ offsets, int n, int nb, int total) {
    __shared__ int sh[256];
    const int t = threadIdx.x;
    const int bid = blockIdx.x;
    sh[t] = (t < nb && t < bid) ? bsum[t] : 0;
    __syncthreads();
    #pragma unroll
    for (int d = 128; d > 0; d >>= 1) {
        if (t < d) sh[t] += sh[t + d];
        __syncthreads();
    }
    const int boff = sh[0];
    const int i = bid * 256 + t;
    if (i < n) offsets[i] = pre[i] + boff;
    if (i == 0) offsets[n] = total;
}

// atomic-free fill: position = offsets[dst] + rank (rank from hist)
__global__ void fill_k(const int* __restrict__ src, const int* __restrict__ dst,
                       const int* __restrict__ rank, int E,
                       const int* __restrict__ offsets, int* __restrict__ sorted_src) {
    int i = blockIdx.x * blockDim.x + threadIdx.x;
    if (i < E) __builtin_nontemporal_store(src[i], &sorted_src[offsets[dst[i]] + rank[i]]);
}

// ---------------------------------------------------------------------------
// Aggregate fp16 message rows (512 B), fp32 accumulate, fp16 out into
// hcat cols 256..511. Unroll-8: 8 independent row loads in flight per wave.
// Output stores are nontemporal: keeps the 25.6 MB gather table from being
// evicted by agg's own write-allocate traffic. (r12 lesson: slicing cut FETCH
// but tripled VALU; this row-gather form is the proven operating point.)
// ---------------------------------------------------------------------------
__global__ void agg_k(const u16* __restrict__ t, const int* __restrict__ offsets,
                      const int* __restrict__ sorted_src,
                      u16* __restrict__ out, int n) {
    const int node = blockIdx.x * (blockDim.x >> 6) + (threadIdx.x >> 6);
    const int lane = threadIdx.x & 63;
    if (node >= n) return;
    const int s0 = offsets[node], s1 = offsets[node + 1];

    float4 a0 = make_float4(0.f, 0.f, 0.f, 0.f);
    float4 a1 = a0, a2 = a0, a3 = a0;

    int i = s0;
    for (; i + 8 <= s1; i += 8) {
        int e0 = sorted_src[i];
        int e1 = sorted_src[i + 1];
        int e2 = sorted_src[i + 2];
        int e3 = sorted_src[i + 3];
        int e4 = sorted_src[i + 4];
        int e5 = sorted_src[i + 5];
        int e6 = sorted_src[i + 6];
        int e7 = sorted_src[i + 7];
        ushort4 v0 = *reinterpret_cast<const ushort4*>(t + (size_t)e0 * 256 + lane * 4);
        ushort4 v1 = *reinterpret_cast<const ushort4*>(t + (size_t)e1 * 256 + lane * 4);
        ushort4 v2 = *reinterpret_cast<const ushort4*>(t + (size_t)e2 * 256 + lane * 4);
        ushort4 v3 = *reinterpret_cast<const ushort4*>(t + (size_t)e3 * 256 + lane * 4);
        ushort4 v4 = *reinterpret_cast<const ushort4*>(t + (size_t)e4 * 256 + lane * 4);
        ushort4 v5 = *reinterpret_cast<const ushort4*>(t + (size_t)e5 * 256 + lane * 4);
        ushort4 v6 = *reinterpret_cast<const ushort4*>(t + (size_t)e6 * 256 + lane * 4);
        ushort4 v7 = *reinterpret_cast<const ushort4*>(t + (size_t)e7 * 256 + lane * 4);
        a0.x += h2f(v0.x); a0.y += h2f(v0.y); a0.z += h2f(v0.z); a0.w += h2f(v0.w);
        a1.x += h2f(v1.x); a1.y += h2f(v1.y); a1.z += h2f(v1.z); a1.w += h2f(v1.w);
        a2.x += h2f(v2.x); a2.y += h2f(v2.y); a2.z += h2f(v2.z); a2.w += h2f(v2.w);
        a3.x += h2f(v3.x); a3.y += h2f(v3.y); a3.z += h2f(v3.z); a3.w += h2f(v3.w);
        a0.x += h2f(v4.x); a0.y += h2f(v4.y); a0.z += h2f(v4.z); a0.w += h2f(v4.w);
        a1.x += h2f(v5.x); a1.y += h2f(v5.y); a1.z += h2f(v5.z); a1.w += h2f(v5.w);
        a2.x += h2f(v6.x); a2.y += h2f(v6.y); a2.z += h2f(v6.z); a2.w += h2f(v6.w);
        a3.x += h2f(v7.x); a3.y += h2f(v7.y); a3.z += h2f(v7.z); a3.w += h2f(v7.w);
    }
    for (; i + 4 <= s1; i += 4) {
        int e0 = sorted_src[i];
        int e1 = sorted_src[i + 1];
        int e2 = sorted_src[i + 2];
        int e3 = sorted_src[i + 3];
        ushort4 v0 = *reinterpret_cast<const ushort4*>(t + (size_t)e0 * 256 + lane * 4);
        ushort4 v1 = *reinterpret_cast<const ushort4*>(t + (size_t)e1 * 256 + lane * 4);
        ushort4 v2 = *reinterpret_cast<const ushort4*>(t + (size_t)e2 * 256 + lane * 4);
        ushort4 v3 = *reinterpret_cast<const ushort4*>(t + (size_t)e3 * 256 + lane * 4);
        a0.x += h2f(v0.x); a0.y += h2f(v0.y); a0.z += h2f(v0.z); a0.w += h2f(v0.w);
        a1.x += h2f(v1.x); a1.y += h2f(v1.y); a1.z += h2f(v1.z); a1.w += h2f(v1.w);
        a2.x += h2f(v2.x); a2.y += h2f(v2.y); a2.z += h2f(v2.z); a2.w += h2f(v2.w);
        a3.x += h2f(v3.x); a3.y += h2f(v3.y); a3.z += h2f(v3.z); a3.w += h2f(v3.w);
    }
    for (; i < s1; ++i) {
        int e0 = sorted_src[i];
        ushort4 v0 = *reinterpret_cast<const ushort4*>(t + (size_t)e0 * 256 + lane * 4);
        a0.x += h2f(v0.x); a0.y += h2f(v0.y); a0.z += h2f(v0.z); a0.w += h2f(v0.w);
    }
    float4 acc;
    acc.x = (a0.x + a1.x) + (a2.x + a3.x);
    acc.y = (a0.y + a1.y) + (a2.y + a3.y);
    acc.z = (a0.z + a1.z) + (a2.z + a3.z);
    acc.w = (a0.w + a1.w) + (a2.w + a3.w);

    ushort4 h4;
    h4.x = f2h(acc.x); h4.y = f2h(acc.y); h4.z = f2h(acc.z); h4.w = f2h(acc.w);
    u64 packed = (u64)h4.x | ((u64)h4.y << 16) | ((u64)h4.z << 32) | ((u64)h4.w << 48);
    __builtin_nontemporal_store(packed,
        reinterpret_cast<u64*>(out + (size_t)node * 512 + 256 + (size_t)lane * 4));
}

// ---------------------------------------------------------------------------
extern "C" void kernel_launch(void* const* d_in, const int* in_sizes, int n_in,
                              void* d_out, int out_size, void* d_ws, size_t ws_size,
                              hipStream_t stream) {
    const float* x       = (const float*)d_in[0];
    const int*   edges   = (const int*)d_in[1];
    const float* pre_w1  = (const float*)d_in[2];
    const float* pre_b1  = (const float*)d_in[3];
    const float* pre_w2  = (const float*)d_in[4];
    const float* pre_b2  = (const float*)d_in[5];
    const float* conv_w  = (const float*)d_in[6];
    const float* conv_b  = (const float*)d_in[7];
    const float* post_w1 = (const float*)d_in[8];
    const float* post_b1 = (const float*)d_in[9];
    const float* post_w2 = (const float*)d_in[10];
    const float* post_b2 = (const float*)d_in[11];

    const int N = in_sizes[0] / 16;
    const int E = in_sizes[1] / 2;
    const int* src = edges;
    const int* dst = edges + E;

    const int Mp128 = (N + 127) & ~127;

    // workspace layout (~85 MB)
    u16*   hcat = (u16*)d_ws;                              // Mp128 x 512 fp16: [t0 | agg]
    u16*   tf16 = hcat + (size_t)Mp128 * 512;              // Mp128 x 256 fp16
    u16*   wcT  = tf16 + (size_t)Mp128 * 256;              // 256 x 256 fp16 (W2@Wc)^T
    u16*   zWT  = wcT + 256 * 256;                         // 256 x 512 fp16 [(W2@P1h)^T | P1a^T]
    u16*   p2T  = zWT + 256 * 512;                         // 16 x 256 fp16
    float* btc  = (float*)(p2T + 16 * 256);                // 256 f32
    float* bzc  = btc + 256;                               // 256 f32
    int* offsets = (int*)(bzc + 256);                      // N+1
    int* counts  = offsets + (N + 1);                      // N
    int* rank    = counts + N;                             // E
    int* sorted  = rank + E;                               // E
    int* pre     = sorted + E;                             // N
    int* bsum    = pre + N;                                // <=256

    const dim3 blk(256);
    const int nsb  = (N + 255) / 256;
    const int npre = (N + 15) / 16;

    // fused setup: weight prep + counts zeroing + pre-MLP layer 1 (r14 form)
    setup_k<<<786 + nsb + npre, blk, 0, stream>>>(
        pre_w2, pre_b2, conv_w, conv_b, post_w1, post_b1, post_w2,
        x, pre_w1, pre_b1,
        wcT, btc, zWT, bzc, p2T, counts, hcat, nsb, N);

    // CSR by destination (rank trick: fill is atomic-free)
    hist_k<<<(E + 255) / 256, blk, 0, stream>>>(dst, E, counts, rank);
    scan1_k<<<nsb, blk, 0, stream>>>(counts, pre, bsum, N);
    scan3_k<<<nsb, blk, 0, stream>>>(pre, bsum, offsets, N, nsb, E);
    fill_k<<<(E + 255) / 256, blk, 0, stream>>>(src, dst, rank, E, offsets, sorted);

    // t = relu(t0 @ (W2@Wc) + btc) -> tf16
    mfma_k<1><<<Mp128 / 128, dim3(512), 0, stream>>>(hcat, 512, wcT, btc,
                                                     tf16, 256, N, 256);
    // aggregate fp16 rows -> hcat[:, 256:]
    agg_k<<<(N + 3) / 4, blk, 0, stream>>>(tf16, offsets, sorted, hcat, N);
    // z = relu([t0|agg] @ zWT + bzc); out = tanh(z @ p2 + b2)  (fused)
    mfmaz_k<<<Mp128 / 128, dim3(512), 0, stream>>>(hcat, 512, zWT, bzc,
                                                   p2T, post_b2, (float*)d_out, N, 512);
}

// Round 18
// 178.132 us; speedup vs baseline: 1.1222x; 1.1222x over previous
//
#include <hip/hip_runtime.h>
#include <hip/hip_bf16.h>

using f16x8 = __attribute__((ext_vector_type(8))) _Float16;  // 8 fp16 (4 VGPRs)
using f32x4 = __attribute__((ext_vector_type(4))) float;
using u16 = unsigned short;

__device__ __forceinline__ u16 f2h(float v) {
    _Float16 h = (_Float16)v;
    u16 r; __builtin_memcpy(&r, &h, 2); return r;
}
__device__ __forceinline__ float h2f(u16 x) {
    _Float16 h; __builtin_memcpy(&h, &x, 2); return (float)h;
}

// bank-decorrelation XOR: chunk permutation within a row's 4x16B chunks
__device__ __forceinline__ int fsw(int row) { return (row & 3) ^ ((row >> 2) & 3); }
__device__ __forceinline__ int aoff(int row, int kq) {
    return row * 32 + ((kq ^ fsw(row)) * 8);
}

// async global->LDS DMA, 16B per lane; LDS dest = wave-uniform base + lane*16
__device__ __forceinline__ void gl16(const u16* g, const u16* l) {
    __builtin_amdgcn_global_load_lds(
        (const __attribute__((address_space(1))) unsigned int*)g,
        (__attribute__((address_space(3))) unsigned int*)l, 16, 0, 0);
}

// ---------------------------------------------------------------------------
// fp16 MFMA GEMM (fp32 accumulate): tile 128 rows x 256 cols, BK=32.
// 512 threads = 8 waves (2x4); each wave owns a 64x64 output tile.
// launch_bounds(512,4): 4 waves/SIMD; (512,6) would force <=85 unified
// VGPR+AGPR/wave and spill the 64-AGPR accumulator (round-10: 155 MB spill).
// (round-17 lesson: NT stores on outputs consumed by later kernels bypass L2
//  and cost +20 us total — keep plain stores.)
// ---------------------------------------------------------------------------
template<int ACT>
__global__ __launch_bounds__(512, 4)
void mfma_k(const u16* __restrict__ A, int lda,
            const u16* __restrict__ BT,
            const float* __restrict__ bias,
            u16* __restrict__ Ch,
            int ldc, int M, int K) {
    __shared__ u16 As[2][128 * 32];   // 8 KB x2
    __shared__ u16 Bs[2][256 * 32];   // 16 KB x2

    const int tid  = threadIdx.x;
    const int brow = blockIdx.x * 128;
    const int lane = tid & 63;
    const int w    = tid >> 6;
    const int wr = w >> 2, wc = w & 3;
    const int lr = lane & 15, lq = lane >> 4;

    const int rsub = lane >> 2;
    const int s    = lane & 3;
    const int rowA  = w * 16 + rsub;
    const int rowB0 = w * 16 + rsub;
    const int rowB1 = 128 + w * 16 + rsub;
    const u16* gA  = A  + (size_t)(brow + rowA) * lda + (s ^ fsw(rowA))  * 8;
    const u16* gB0 = BT + (size_t)rowB0        * K   + (s ^ fsw(rowB0)) * 8;
    const u16* gB1 = BT + (size_t)rowB1        * K   + (s ^ fsw(rowB1)) * 8;

    f32x4 acc[4][4] = {};

#define STAGE(buf, koff)                                                       \
    do {                                                                       \
        gl16(gA  + (koff), &As[buf][w * 512]);                                 \
        gl16(gB0 + (koff), &Bs[buf][w * 512]);                                 \
        gl16(gB1 + (koff), &Bs[buf][(8 + w) * 512]);                           \
    } while (0)

    STAGE(0, 0);
    __syncthreads();

    const int nt = K >> 5;
    int cur = 0;
    for (int t = 0; t < nt; ++t) {
        if (t + 1 < nt) STAGE(cur ^ 1, (t + 1) * 32);

        f16x8 bf[4];
        #pragma unroll
        for (int n = 0; n < 4; ++n)
            bf[n] = *reinterpret_cast<const f16x8*>(&Bs[cur][aoff(wc * 64 + n * 16 + lr, lq)]);
        #pragma unroll
        for (int m = 0; m < 4; ++m) {
            f16x8 af = *reinterpret_cast<const f16x8*>(&As[cur][aoff(wr * 64 + m * 16 + lr, lq)]);
            #pragma unroll
            for (int n = 0; n < 4; ++n)
                acc[m][n] = __builtin_amdgcn_mfma_f32_16x16x32_f16(af, bf[n], acc[m][n], 0, 0, 0);
        }

        if (t + 1 < nt) {
            __syncthreads();
            cur ^= 1;
        }
    }
#undef STAGE

    // epilogue: frag layout col=lane&15, row=(lane>>4)*4+r (m89-verified)
    #pragma unroll
    for (int m = 0; m < 4; ++m) {
        #pragma unroll
        for (int n = 0; n < 4; ++n) {
            #pragma unroll
            for (int r = 0; r < 4; ++r) {
                int grow = brow + wr * 64 + m * 16 + lq * 4 + r;
                if (grow >= M) continue;
                int gcol = wc * 64 + n * 16 + lr;
                float v = acc[m][n][r] + bias[gcol];
                if (ACT == 1) v = fmaxf(v, 0.f);
                Ch[(size_t)grow * ldc + gcol] = f2h(v);
            }
        }
    }
}

// ---------------------------------------------------------------------------
// Fused z+output kernel: z = relu([t0|agg] @ zWT + bzc)   (tile 128x256, K=512)
// then out = tanh(z @ p2 + b2) in-kernel via z->LDS (aliased over staging pool)
// and two 128-col MFMA phases. z never touches HBM.
// ---------------------------------------------------------------------------
__global__ __launch_bounds__(512, 4)
void mfmaz_k(const u16* __restrict__ A, int lda,
             const u16* __restrict__ BT,
             const float* __restrict__ bias,
             const u16* __restrict__ P2T, const float* __restrict__ b2,
             float* __restrict__ out, int M, int K) {
    __shared__ u16 pool[2 * 128 * 32 + 2 * 256 * 32];   // 48 KB
    u16 (*As)[128 * 32] = reinterpret_cast<u16(*)[128 * 32]>(pool);
    u16 (*Bs)[256 * 32] = reinterpret_cast<u16(*)[256 * 32]>(pool + 2 * 128 * 32);
    u16 (*zs)[136]      = reinterpret_cast<u16(*)[136]>(pool);  // 128 x 136 = 34 KB

    const int tid  = threadIdx.x;
    const int brow = blockIdx.x * 128;
    const int lane = tid & 63;
    const int w    = tid >> 6;
    const int wr = w >> 2, wc = w & 3;
    const int lr = lane & 15, lq = lane >> 4;

    const int rsub = lane >> 2;
    const int s    = lane & 3;
    const int rowA  = w * 16 + rsub;
    const int rowB0 = w * 16 + rsub;
    const int rowB1 = 128 + w * 16 + rsub;
    const u16* gA  = A  + (size_t)(brow + rowA) * lda + (s ^ fsw(rowA))  * 8;
    const u16* gB0 = BT + (size_t)rowB0        * K   + (s ^ fsw(rowB0)) * 8;
    const u16* gB1 = BT + (size_t)rowB1        * K   + (s ^ fsw(rowB1)) * 8;

    f32x4 acc[4][4] = {};

#define STAGE(buf, koff)                                                       \
    do {                                                                       \
        gl16(gA  + (koff), &As[buf][w * 512]);                                 \
        gl16(gB0 + (koff), &Bs[buf][w * 512]);                                 \
        gl16(gB1 + (koff), &Bs[buf][(8 + w) * 512]);                           \
    } while (0)

    STAGE(0, 0);
    __syncthreads();

    const int nt = K >> 5;
    int cur = 0;
    for (int t = 0; t < nt; ++t) {
        if (t + 1 < nt) STAGE(cur ^ 1, (t + 1) * 32);

        f16x8 bf[4];
        #pragma unroll
        for (int n = 0; n < 4; ++n)
            bf[n] = *reinterpret_cast<const f16x8*>(&Bs[cur][aoff(wc * 64 + n * 16 + lr, lq)]);
        #pragma unroll
        for (int m = 0; m < 4; ++m) {
            f16x8 af = *reinterpret_cast<const f16x8*>(&As[cur][aoff(wr * 64 + m * 16 + lr, lq)]);
            #pragma unroll
            for (int n = 0; n < 4; ++n)
                acc[m][n] = __builtin_amdgcn_mfma_f32_16x16x32_f16(af, bf[n], acc[m][n], 0, 0, 0);
        }

        if (t + 1 < nt) {
            __syncthreads();
            cur ^= 1;
        }
    }
#undef STAGE

    __syncthreads();   // all As/Bs reads done; pool may be reused as zs

    // two phases over z columns: phase p covers z cols [128p, 128p+128)
    f32x4 acc2 = {};
    #pragma unroll
    for (int p = 0; p < 2; ++p) {
        if ((wc >> 1) == p) {
            const int colp = (wc & 1) * 64;
            #pragma unroll
            for (int m = 0; m < 4; ++m) {
                #pragma unroll
                for (int n = 0; n < 4; ++n) {
                    #pragma unroll
                    for (int r = 0; r < 4; ++r) {
                        int row  = wr * 64 + m * 16 + lq * 4 + r;
                        int gcol = wc * 64 + n * 16 + lr;
                        float v = fmaxf(acc[m][n][r] + bias[gcol], 0.f);
                        zs[row][colp + n * 16 + lr] = f2h(v);
                    }
                }
            }
        }
        __syncthreads();
        #pragma unroll
        for (int ks = 0; ks < 4; ++ks) {
            f16x8 af = *reinterpret_cast<const f16x8*>(&zs[w * 16 + lr][ks * 32 + lq * 8]);
            f16x8 bf = *reinterpret_cast<const f16x8*>(P2T + lr * 256 + p * 128 + ks * 32 + lq * 8);
            acc2 = __builtin_amdgcn_mfma_f32_16x16x32_f16(af, bf, acc2, 0, 0, 0);
        }
        __syncthreads();
    }

    const float b = b2[lr];
    #pragma unroll
    for (int r = 0; r < 4; ++r) {
        int grow = brow + w * 16 + lq * 4 + r;
        if (grow < M) out[(size_t)grow * 16 + lr] = tanhf(acc2[r] + b);
    }
}

// ---------------------------------------------------------------------------
// Fused setup (one launch):
//   blocks [0,257)              : wcT = (W2@Wc)^T fp16 (+ bias row -> btc)
//   blocks [257,514)            : zWT[:, :256] = (W2@P1h)^T fp16 (+ bias -> bzc)
//   blocks [514,770)            : zWT[:, 256:] = P1a^T fp16
//   blocks [770,786)            : p2T = post_w2^T fp16
//   blocks [786, 786+nsb)       : counts[i] = 0
//   blocks [786+nsb, ...)       : pre-MLP layer 1 (16 rows/block) -> hcat
// (r15 lesson: hist's atomics fused here cost +30 us — hist stays standalone.)
// ---------------------------------------------------------------------------
__global__ __launch_bounds__(256)
void setup_k(const float* __restrict__ pre_w2, const float* __restrict__ pre_b2,
             const float* __restrict__ conv_w, const float* __restrict__ conv_b,
             const float* __restrict__ post_w1, const float* __restrict__ post_b1,
             const float* __restrict__ post_w2,
             const float* __restrict__ x, const float* __restrict__ pre_w1,
             const float* __restrict__ pre_b1,
             u16* __restrict__ wcT, float* __restrict__ btc,
             u16* __restrict__ zWT, float* __restrict__ bzc,
             u16* __restrict__ p2T, int* __restrict__ counts,
             u16* __restrict__ t0, int nsb, int N) {
    const int b = blockIdx.x;
    const int n = threadIdx.x;
    if (b < 514) {
        const bool second = (b >= 257);
        const int k = second ? (b - 257) : b;
        const float* B    = second ? post_w1 : conv_w;
        const float* addv = second ? post_b1 : conv_b;
        u16*  WT   = second ? zWT : wcT;
        float* bo  = second ? bzc : btc;
        const int ldout = second ? 512 : 256;
        __shared__ float a_sh[256];
        const bool isBias = (k == 256);
        a_sh[n] = isBias ? pre_b2[n] : pre_w2[(size_t)k * 256 + n];
        __syncthreads();
        float s = 0.f;
        #pragma unroll 8
        for (int j = 0; j < 256; ++j)
            s = fmaf(a_sh[j], B[(size_t)j * 256 + n], s);
        if (isBias) bo[n] = s + addv[n];
        else        WT[(size_t)n * ldout + k] = f2h(s);
    } else if (b < 770) {
        const int j = b - 514;
        zWT[(size_t)j * 512 + 256 + n] = f2h(post_w1[(size_t)(256 + n) * 256 + j]);
    } else if (b < 786) {
        const int j = b - 770;
        p2T[(size_t)j * 256 + n] = f2h(post_w2[(size_t)n * 16 + j]);
    } else if (b < 786 + nsb) {
        const int i = (b - 786) * 256 + n;
        if (i < N) counts[i] = 0;
    } else {
        // pre-MLP layer 1, 16 rows per block
        __shared__ float ws[16 * 256];
        __shared__ float xs[16][17];
        const int r0 = (b - 786 - nsb) * 16;
        for (int i = n; i < 16 * 256; i += 256) ws[i] = pre_w1[i];
        {
            int rr = n >> 4, cc = n & 15;
            xs[rr][cc] = (r0 + rr < N) ? x[(size_t)(r0 + rr) * 16 + cc] : 0.f;
        }
        __syncthreads();
        const float bb = pre_b1[n];
        for (int r = 0; r < 16; r++) {
            if (r0 + r >= N) break;
            float acc = bb;
            #pragma unroll
            for (int k = 0; k < 16; k++) acc = fmaf(xs[r][k], ws[k * 256 + n], acc);
            t0[(size_t)(r0 + r) * 512 + n] = f2h(fmaxf(acc, 0.f));
        }
    }
}

// ---------------------------------------------------------------------------
// CSR-by-destination build (rank trick: no atomics in fill)
// ---------------------------------------------------------------------------
__global__ void hist_k(const int* __restrict__ dst, int E,
                       int* __restrict__ counts, int* __restrict__ rank) {
    int i = blockIdx.x * blockDim.x + threadIdx.x;
    if (i < E) rank[i] = atomicAdd(&counts[dst[i]], 1);
}

__global__ __launch_bounds__(256)
void scan1_k(const int* __restrict__ counts, int* __restrict__ pre,
             int* __restrict__ bsum, int n) {
    __shared__ int sh[256];
    const int t = threadIdx.x;
    const int i = blockIdx.x * 256 + t;
    int v = (i < n) ? counts[i] : 0;
    sh[t] = v;
    __syncthreads();
    #pragma unroll
    for (int d = 1; d < 256; d <<= 1) {
        int x = (t >= d) ? sh[t - d] : 0;
        __syncthreads();
        sh[t] += x;
        __syncthreads();
    }
    if (i < n) pre[i] = sh[t] - v;
    if (t == 255) bsum[blockIdx.x] = sh[255];
}

// stage 2+3 fused: each block computes its offset = sum(bsum[0..bid)) inline
__global__ __launch_bounds__(256)
void scan3_k(const int* __restrict__ pre, const int* __restrict__ bsum,
             int* __restrict__ offsets, int n, int nb, int total) {
    __shared__ int sh[256];
    const int t = threadIdx.x;
    const int bid = blockIdx.x;
    sh[t] = (t < nb && t < bid) ? bsum[t] : 0;
    __syncthreads();
    #pragma unroll
    for (int d = 128; d > 0; d >>= 1) {
        if (t < d) sh[t] += sh[t + d];
        __syncthreads();
    }
    const int boff = sh[0];
    const int i = bid * 256 + t;
    if (i < n) offsets[i] = pre[i] + boff;
    if (i == 0) offsets[n] = total;
}

// atomic-free fill: position = offsets[dst] + rank (rank from hist)
__global__ void fill_k(const int* __restrict__ src, const int* __restrict__ dst,
                       const int* __restrict__ rank, int E,
                       const int* __restrict__ offsets, int* __restrict__ sorted_src) {
    int i = blockIdx.x * blockDim.x + threadIdx.x;
    if (i < E) sorted_src[offsets[dst[i]] + rank[i]] = src[i];
}

// ---------------------------------------------------------------------------
// Aggregate fp16 message rows (512 B), fp32 accumulate, fp16 out into
// hcat cols 256..511. Unroll-8: 8 independent row loads in flight per wave.
// (r12 lesson: slicing cut FETCH 175->35 MB but tripled VALU -> 126 us;
//  this row-gather form at ~54.5 us is the proven operating point.)
// ---------------------------------------------------------------------------
__global__ void agg_k(const u16* __restrict__ t, const int* __restrict__ offsets,
                      const int* __restrict__ sorted_src,
                      u16* __restrict__ out, int n) {
    const int node = blockIdx.x * (blockDim.x >> 6) + (threadIdx.x >> 6);
    const int lane = threadIdx.x & 63;
    if (node >= n) return;
    const int s0 = offsets[node], s1 = offsets[node + 1];

    float4 a0 = make_float4(0.f, 0.f, 0.f, 0.f);
    float4 a1 = a0, a2 = a0, a3 = a0;

    int i = s0;
    for (; i + 8 <= s1; i += 8) {
        int e0 = sorted_src[i];
        int e1 = sorted_src[i + 1];
        int e2 = sorted_src[i + 2];
        int e3 = sorted_src[i + 3];
        int e4 = sorted_src[i + 4];
        int e5 = sorted_src[i + 5];
        int e6 = sorted_src[i + 6];
        int e7 = sorted_src[i + 7];
        ushort4 v0 = *reinterpret_cast<const ushort4*>(t + (size_t)e0 * 256 + lane * 4);
        ushort4 v1 = *reinterpret_cast<const ushort4*>(t + (size_t)e1 * 256 + lane * 4);
        ushort4 v2 = *reinterpret_cast<const ushort4*>(t + (size_t)e2 * 256 + lane * 4);
        ushort4 v3 = *reinterpret_cast<const ushort4*>(t + (size_t)e3 * 256 + lane * 4);
        ushort4 v4 = *reinterpret_cast<const ushort4*>(t + (size_t)e4 * 256 + lane * 4);
        ushort4 v5 = *reinterpret_cast<const ushort4*>(t + (size_t)e5 * 256 + lane * 4);
        ushort4 v6 = *reinterpret_cast<const ushort4*>(t + (size_t)e6 * 256 + lane * 4);
        ushort4 v7 = *reinterpret_cast<const ushort4*>(t + (size_t)e7 * 256 + lane * 4);
        a0.x += h2f(v0.x); a0.y += h2f(v0.y); a0.z += h2f(v0.z); a0.w += h2f(v0.w);
        a1.x += h2f(v1.x); a1.y += h2f(v1.y); a1.z += h2f(v1.z); a1.w += h2f(v1.w);
        a2.x += h2f(v2.x); a2.y += h2f(v2.y); a2.z += h2f(v2.z); a2.w += h2f(v2.w);
        a3.x += h2f(v3.x); a3.y += h2f(v3.y); a3.z += h2f(v3.z); a3.w += h2f(v3.w);
        a0.x += h2f(v4.x); a0.y += h2f(v4.y); a0.z += h2f(v4.z); a0.w += h2f(v4.w);
        a1.x += h2f(v5.x); a1.y += h2f(v5.y); a1.z += h2f(v5.z); a1.w += h2f(v5.w);
        a2.x += h2f(v6.x); a2.y += h2f(v6.y); a2.z += h2f(v6.z); a2.w += h2f(v6.w);
        a3.x += h2f(v7.x); a3.y += h2f(v7.y); a3.z += h2f(v7.z); a3.w += h2f(v7.w);
    }
    for (; i + 4 <= s1; i += 4) {
        int e0 = sorted_src[i];
        int e1 = sorted_src[i + 1];
        int e2 = sorted_src[i + 2];
        int e3 = sorted_src[i + 3];
        ushort4 v0 = *reinterpret_cast<const ushort4*>(t + (size_t)e0 * 256 + lane * 4);
        ushort4 v1 = *reinterpret_cast<const ushort4*>(t + (size_t)e1 * 256 + lane * 4);
        ushort4 v2 = *reinterpret_cast<const ushort4*>(t + (size_t)e2 * 256 + lane * 4);
        ushort4 v3 = *reinterpret_cast<const ushort4*>(t + (size_t)e3 * 256 + lane * 4);
        a0.x += h2f(v0.x); a0.y += h2f(v0.y); a0.z += h2f(v0.z); a0.w += h2f(v0.w);
        a1.x += h2f(v1.x); a1.y += h2f(v1.y); a1.z += h2f(v1.z); a1.w += h2f(v1.w);
        a2.x += h2f(v2.x); a2.y += h2f(v2.y); a2.z += h2f(v2.z); a2.w += h2f(v2.w);
        a3.x += h2f(v3.x); a3.y += h2f(v3.y); a3.z += h2f(v3.z); a3.w += h2f(v3.w);
    }
    for (; i < s1; ++i) {
        int e0 = sorted_src[i];
        ushort4 v0 = *reinterpret_cast<const ushort4*>(t + (size_t)e0 * 256 + lane * 4);
        a0.x += h2f(v0.x); a0.y += h2f(v0.y); a0.z += h2f(v0.z); a0.w += h2f(v0.w);
    }
    float4 acc;
    acc.x = (a0.x + a1.x) + (a2.x + a3.x);
    acc.y = (a0.y + a1.y) + (a2.y + a3.y);
    acc.z = (a0.z + a1.z) + (a2.z + a3.z);
    acc.w = (a0.w + a1.w) + (a2.w + a3.w);

    ushort4 h4;
    h4.x = f2h(acc.x); h4.y = f2h(acc.y); h4.z = f2h(acc.z); h4.w = f2h(acc.w);
    *reinterpret_cast<ushort4*>(out + (size_t)node * 512 + 256 + (size_t)lane * 4) = h4;
}

// ---------------------------------------------------------------------------
extern "C" void kernel_launch(void* const* d_in, const int* in_sizes, int n_in,
                              void* d_out, int out_size, void* d_ws, size_t ws_size,
                              hipStream_t stream) {
    const float* x       = (const float*)d_in[0];
    const int*   edges   = (const int*)d_in[1];
    const float* pre_w1  = (const float*)d_in[2];
    const float* pre_b1  = (const float*)d_in[3];
    const float* pre_w2  = (const float*)d_in[4];
    const float* pre_b2  = (const float*)d_in[5];
    const float* conv_w  = (const float*)d_in[6];
    const float* conv_b  = (const float*)d_in[7];
    const float* post_w1 = (const float*)d_in[8];
    const float* post_b1 = (const float*)d_in[9];
    const float* post_w2 = (const float*)d_in[10];
    const float* post_b2 = (const float*)d_in[11];

    const int N = in_sizes[0] / 16;
    const int E = in_sizes[1] / 2;
    const int* src = edges;
    const int* dst = edges + E;

    const int Mp128 = (N + 127) & ~127;

    // workspace layout (~85 MB)
    u16*   hcat = (u16*)d_ws;                              // Mp128 x 512 fp16: [t0 | agg]
    u16*   tf16 = hcat + (size_t)Mp128 * 512;              // Mp128 x 256 fp16
    u16*   wcT  = tf16 + (size_t)Mp128 * 256;              // 256 x 256 fp16 (W2@Wc)^T
    u16*   zWT  = wcT + 256 * 256;                         // 256 x 512 fp16 [(W2@P1h)^T | P1a^T]
    u16*   p2T  = zWT + 256 * 512;                         // 16 x 256 fp16
    float* btc  = (float*)(p2T + 16 * 256);                // 256 f32
    float* bzc  = btc + 256;                               // 256 f32
    int* offsets = (int*)(bzc + 256);                      // N+1
    int* counts  = offsets + (N + 1);                      // N
    int* rank    = counts + N;                             // E
    int* sorted  = rank + E;                               // E
    int* pre     = sorted + E;                             // N
    int* bsum    = pre + N;                                // <=256

    const dim3 blk(256);
    const int nsb  = (N + 255) / 256;
    const int npre = (N + 15) / 16;

    // fused setup: weight prep + counts zeroing + pre-MLP layer 1
    setup_k<<<786 + nsb + npre, blk, 0, stream>>>(
        pre_w2, pre_b2, conv_w, conv_b, post_w1, post_b1, post_w2,
        x, pre_w1, pre_b1,
        wcT, btc, zWT, bzc, p2T, counts, hcat, nsb, N);

    // CSR by destination (rank trick: fill is atomic-free)
    hist_k<<<(E + 255) / 256, blk, 0, stream>>>(dst, E, counts, rank);
    scan1_k<<<nsb, blk, 0, stream>>>(counts, pre, bsum, N);
    scan3_k<<<nsb, blk, 0, stream>>>(pre, bsum, offsets, N, nsb, E);
    fill_k<<<(E + 255) / 256, blk, 0, stream>>>(src, dst, rank, E, offsets, sorted);

    // t = relu(t0 @ (W2@Wc) + btc) -> tf16
    mfma_k<1><<<Mp128 / 128, dim3(512), 0, stream>>>(hcat, 512, wcT, btc,
                                                     tf16, 256, N, 256);
    // aggregate fp16 rows -> hcat[:, 256:]
    agg_k<<<(N + 3) / 4, blk, 0, stream>>>(tf16, offsets, sorted, hcat, N);
    // z = relu([t0|agg] @ zWT + bzc); out = tanh(z @ p2 + b2)  (fused)
    mfmaz_k<<<Mp128 / 128, dim3(512), 0, stream>>>(hcat, 512, zWT, bzc,
                                                   p2T, post_b2, (float*)d_out, N, 512);
}

// Round 19
// 174.568 us; speedup vs baseline: 1.1451x; 1.0204x over previous
//
#include <hip/hip_runtime.h>
#include <hip/hip_bf16.h>

using f16x8 = __attribute__((ext_vector_type(8))) _Float16;  // 8 fp16 (4 VGPRs)
using f32x4 = __attribute__((ext_vector_type(4))) float;
using u16 = unsigned short;

__device__ __forceinline__ u16 f2h(float v) {
    _Float16 h = (_Float16)v;
    u16 r; __builtin_memcpy(&r, &h, 2); return r;
}
__device__ __forceinline__ float h2f(u16 x) {
    _Float16 h; __builtin_memcpy(&h, &x, 2); return (float)h;
}

// bank-decorrelation XOR: chunk permutation within a row's 4x16B chunks
__device__ __forceinline__ int fsw(int row) { return (row & 3) ^ ((row >> 2) & 3); }
__device__ __forceinline__ int aoff(int row, int kq) {
    return row * 32 + ((kq ^ fsw(row)) * 8);
}

// async global->LDS DMA, 16B per lane; LDS dest = wave-uniform base + lane*16
__device__ __forceinline__ void gl16(const u16* g, const u16* l) {
    __builtin_amdgcn_global_load_lds(
        (const __attribute__((address_space(1))) unsigned int*)g,
        (__attribute__((address_space(3))) unsigned int*)l, 16, 0, 0);
}

// ---------------------------------------------------------------------------
// Fused t-GEMM + CSR-fill (independent work, one grid):
//   blocks [0, NT)   : fp16 MFMA GEMM t = relu(t0 @ wcT + btc), tile 128x256
//   blocks [NT, ...) : atomic-free fill sorted[offsets[dst]+rank] = src
// GEMM: 512 thr = 8 waves (2x4), 64x64 out/wave, BK=32, global_load_lds
// staging, XOR chunk swizzle on source+read. launch_bounds(512,4) — (512,6)
// forces <=85 unified VGPR/wave and spills the 64-AGPR acc (round-10 lesson).
// (r17 lesson: plain stores — NT stores bypass L2 and cost the consumer.)
// ---------------------------------------------------------------------------
__global__ __launch_bounds__(512, 4)
void gemmfill_k(const u16* __restrict__ A, int lda,
                const u16* __restrict__ BT,
                const float* __restrict__ bias,
                u16* __restrict__ Ch,
                int ldc, int M, int K, int NT,
                const int* __restrict__ esrc, const int* __restrict__ edst,
                const int* __restrict__ rank, const int* __restrict__ offsets,
                int* __restrict__ sorted, int E) {
    __shared__ u16 As[2][128 * 32];   // 8 KB x2
    __shared__ u16 Bs[2][256 * 32];   // 16 KB x2

    if (blockIdx.x >= NT) {           // ---- fill branch (block-uniform) ----
        int i = (blockIdx.x - NT) * 512 + threadIdx.x;
        if (i < E) sorted[offsets[edst[i]] + rank[i]] = esrc[i];
        return;
    }

    const int tid  = threadIdx.x;
    const int brow = blockIdx.x * 128;
    const int lane = tid & 63;
    const int w    = tid >> 6;
    const int wr = w >> 2, wc = w & 3;
    const int lr = lane & 15, lq = lane >> 4;

    const int rsub = lane >> 2;
    const int s    = lane & 3;
    const int rowA  = w * 16 + rsub;
    const int rowB0 = w * 16 + rsub;
    const int rowB1 = 128 + w * 16 + rsub;
    const u16* gA  = A  + (size_t)(brow + rowA) * lda + (s ^ fsw(rowA))  * 8;
    const u16* gB0 = BT + (size_t)rowB0        * K   + (s ^ fsw(rowB0)) * 8;
    const u16* gB1 = BT + (size_t)rowB1        * K   + (s ^ fsw(rowB1)) * 8;

    f32x4 acc[4][4] = {};

#define STAGE(buf, koff)                                                       \
    do {                                                                       \
        gl16(gA  + (koff), &As[buf][w * 512]);                                 \
        gl16(gB0 + (koff), &Bs[buf][w * 512]);                                 \
        gl16(gB1 + (koff), &Bs[buf][(8 + w) * 512]);                           \
    } while (0)

    STAGE(0, 0);
    __syncthreads();

    const int nt = K >> 5;
    int cur = 0;
    for (int t = 0; t < nt; ++t) {
        if (t + 1 < nt) STAGE(cur ^ 1, (t + 1) * 32);

        f16x8 bf[4];
        #pragma unroll
        for (int n = 0; n < 4; ++n)
            bf[n] = *reinterpret_cast<const f16x8*>(&Bs[cur][aoff(wc * 64 + n * 16 + lr, lq)]);
        #pragma unroll
        for (int m = 0; m < 4; ++m) {
            f16x8 af = *reinterpret_cast<const f16x8*>(&As[cur][aoff(wr * 64 + m * 16 + lr, lq)]);
            #pragma unroll
            for (int n = 0; n < 4; ++n)
                acc[m][n] = __builtin_amdgcn_mfma_f32_16x16x32_f16(af, bf[n], acc[m][n], 0, 0, 0);
        }

        if (t + 1 < nt) {
            __syncthreads();
            cur ^= 1;
        }
    }
#undef STAGE

    // epilogue: frag layout col=lane&15, row=(lane>>4)*4+r (m89-verified)
    #pragma unroll
    for (int m = 0; m < 4; ++m) {
        #pragma unroll
        for (int n = 0; n < 4; ++n) {
            #pragma unroll
            for (int r = 0; r < 4; ++r) {
                int grow = brow + wr * 64 + m * 16 + lq * 4 + r;
                if (grow >= M) continue;
                int gcol = wc * 64 + n * 16 + lr;
                float v = fmaxf(acc[m][n][r] + bias[gcol], 0.f);
                Ch[(size_t)grow * ldc + gcol] = f2h(v);
            }
        }
    }
}

// ---------------------------------------------------------------------------
// Fused z+output kernel: z = relu([t0|agg] @ zWT + bzc)   (tile 128x256, K=512)
// then out = tanh(z @ p2 + b2) in-kernel via z->LDS (aliased over staging pool)
// and two 128-col MFMA phases. z never touches HBM.
// ---------------------------------------------------------------------------
__global__ __launch_bounds__(512, 4)
void mfmaz_k(const u16* __restrict__ A, int lda,
             const u16* __restrict__ BT,
             const float* __restrict__ bias,
             const u16* __restrict__ P2T, const float* __restrict__ b2,
             float* __restrict__ out, int M, int K) {
    __shared__ u16 pool[2 * 128 * 32 + 2 * 256 * 32];   // 48 KB
    u16 (*As)[128 * 32] = reinterpret_cast<u16(*)[128 * 32]>(pool);
    u16 (*Bs)[256 * 32] = reinterpret_cast<u16(*)[256 * 32]>(pool + 2 * 128 * 32);
    u16 (*zs)[136]      = reinterpret_cast<u16(*)[136]>(pool);  // 128 x 136 = 34 KB

    const int tid  = threadIdx.x;
    const int brow = blockIdx.x * 128;
    const int lane = tid & 63;
    const int w    = tid >> 6;
    const int wr = w >> 2, wc = w & 3;
    const int lr = lane & 15, lq = lane >> 4;

    const int rsub = lane >> 2;
    const int s    = lane & 3;
    const int rowA  = w * 16 + rsub;
    const int rowB0 = w * 16 + rsub;
    const int rowB1 = 128 + w * 16 + rsub;
    const u16* gA  = A  + (size_t)(brow + rowA) * lda + (s ^ fsw(rowA))  * 8;
    const u16* gB0 = BT + (size_t)rowB0        * K   + (s ^ fsw(rowB0)) * 8;
    const u16* gB1 = BT + (size_t)rowB1        * K   + (s ^ fsw(rowB1)) * 8;

    f32x4 acc[4][4] = {};

#define STAGE(buf, koff)                                                       \
    do {                                                                       \
        gl16(gA  + (koff), &As[buf][w * 512]);                                 \
        gl16(gB0 + (koff), &Bs[buf][w * 512]);                                 \
        gl16(gB1 + (koff), &Bs[buf][(8 + w) * 512]);                           \
    } while (0)

    STAGE(0, 0);
    __syncthreads();

    const int nt = K >> 5;
    int cur = 0;
    for (int t = 0; t < nt; ++t) {
        if (t + 1 < nt) STAGE(cur ^ 1, (t + 1) * 32);

        f16x8 bf[4];
        #pragma unroll
        for (int n = 0; n < 4; ++n)
            bf[n] = *reinterpret_cast<const f16x8*>(&Bs[cur][aoff(wc * 64 + n * 16 + lr, lq)]);
        #pragma unroll
        for (int m = 0; m < 4; ++m) {
            f16x8 af = *reinterpret_cast<const f16x8*>(&As[cur][aoff(wr * 64 + m * 16 + lr, lq)]);
            #pragma unroll
            for (int n = 0; n < 4; ++n)
                acc[m][n] = __builtin_amdgcn_mfma_f32_16x16x32_f16(af, bf[n], acc[m][n], 0, 0, 0);
        }

        if (t + 1 < nt) {
            __syncthreads();
            cur ^= 1;
        }
    }
#undef STAGE

    __syncthreads();   // all As/Bs reads done; pool may be reused as zs

    // two phases over z columns: phase p covers z cols [128p, 128p+128)
    f32x4 acc2 = {};
    #pragma unroll
    for (int p = 0; p < 2; ++p) {
        if ((wc >> 1) == p) {
            const int colp = (wc & 1) * 64;
            #pragma unroll
            for (int m = 0; m < 4; ++m) {
                #pragma unroll
                for (int n = 0; n < 4; ++n) {
                    #pragma unroll
                    for (int r = 0; r < 4; ++r) {
                        int row  = wr * 64 + m * 16 + lq * 4 + r;
                        int gcol = wc * 64 + n * 16 + lr;
                        float v = fmaxf(acc[m][n][r] + bias[gcol], 0.f);
                        zs[row][colp + n * 16 + lr] = f2h(v);
                    }
                }
            }
        }
        __syncthreads();
        #pragma unroll
        for (int ks = 0; ks < 4; ++ks) {
            f16x8 af = *reinterpret_cast<const f16x8*>(&zs[w * 16 + lr][ks * 32 + lq * 8]);
            f16x8 bf = *reinterpret_cast<const f16x8*>(P2T + lr * 256 + p * 128 + ks * 32 + lq * 8);
            acc2 = __builtin_amdgcn_mfma_f32_16x16x32_f16(af, bf, acc2, 0, 0, 0);
        }
        __syncthreads();
    }

    const float b = b2[lr];
    #pragma unroll
    for (int r = 0; r < 4; ++r) {
        int grow = brow + w * 16 + lq * 4 + r;
        if (grow < M) out[(size_t)grow * 16 + lr] = tanhf(acc2[r] + b);
    }
}

// ---------------------------------------------------------------------------
// Fused setup (one launch):
//   blocks [0,257)              : wcT = (W2@Wc)^T fp16 (+ bias row -> btc)
//   blocks [257,514)            : zWT[:, :256] = (W2@P1h)^T fp16 (+ bias -> bzc)
//   blocks [514,770)            : zWT[:, 256:] = P1a^T fp16
//   blocks [770,786)            : p2T = post_w2^T fp16
//   blocks [786, 786+nsb)       : counts[i] = 0
//   blocks [786+nsb, ...)       : pre-MLP layer 1 (16 rows/block) -> hcat
// (r15 lesson: hist's atomics fused here cost +30 us — hist stays standalone.)
// ---------------------------------------------------------------------------
__global__ __launch_bounds__(256)
void setup_k(const float* __restrict__ pre_w2, const float* __restrict__ pre_b2,
             const float* __restrict__ conv_w, const float* __restrict__ conv_b,
             const float* __restrict__ post_w1, const float* __restrict__ post_b1,
             const float* __restrict__ post_w2,
             const float* __restrict__ x, const float* __restrict__ pre_w1,
             const float* __restrict__ pre_b1,
             u16* __restrict__ wcT, float* __restrict__ btc,
             u16* __restrict__ zWT, float* __restrict__ bzc,
             u16* __restrict__ p2T, int* __restrict__ counts,
             u16* __restrict__ t0, int nsb, int N) {
    const int b = blockIdx.x;
    const int n = threadIdx.x;
    if (b < 514) {
        const bool second = (b >= 257);
        const int k = second ? (b - 257) : b;
        const float* B    = second ? post_w1 : conv_w;
        const float* addv = second ? post_b1 : conv_b;
        u16*  WT   = second ? zWT : wcT;
        float* bo  = second ? bzc : btc;
        const int ldout = second ? 512 : 256;
        __shared__ float a_sh[256];
        const bool isBias = (k == 256);
        a_sh[n] = isBias ? pre_b2[n] : pre_w2[(size_t)k * 256 + n];
        __syncthreads();
        float s = 0.f;
        #pragma unroll 8
        for (int j = 0; j < 256; ++j)
            s = fmaf(a_sh[j], B[(size_t)j * 256 + n], s);
        if (isBias) bo[n] = s + addv[n];
        else        WT[(size_t)n * ldout + k] = f2h(s);
    } else if (b < 770) {
        const int j = b - 514;
        zWT[(size_t)j * 512 + 256 + n] = f2h(post_w1[(size_t)(256 + n) * 256 + j]);
    } else if (b < 786) {
        const int j = b - 770;
        p2T[(size_t)j * 256 + n] = f2h(post_w2[(size_t)n * 16 + j]);
    } else if (b < 786 + nsb) {
        const int i = (b - 786) * 256 + n;
        if (i < N) counts[i] = 0;
    } else {
        // pre-MLP layer 1, 16 rows per block
        __shared__ float ws[16 * 256];
        __shared__ float xs[16][17];
        const int r0 = (b - 786 - nsb) * 16;
        for (int i = n; i < 16 * 256; i += 256) ws[i] = pre_w1[i];
        {
            int rr = n >> 4, cc = n & 15;
            xs[rr][cc] = (r0 + rr < N) ? x[(size_t)(r0 + rr) * 16 + cc] : 0.f;
        }
        __syncthreads();
        const float bb = pre_b1[n];
        for (int r = 0; r < 16; r++) {
            if (r0 + r >= N) break;
            float acc = bb;
            #pragma unroll
            for (int k = 0; k < 16; k++) acc = fmaf(xs[r][k], ws[k * 256 + n], acc);
            t0[(size_t)(r0 + r) * 512 + n] = f2h(fmaxf(acc, 0.f));
        }
    }
}

// ---------------------------------------------------------------------------
// CSR-by-destination build (rank trick: no atomics in fill)
// ---------------------------------------------------------------------------
__global__ void hist_k(const int* __restrict__ dst, int E,
                       int* __restrict__ counts, int* __restrict__ rank) {
    int i = blockIdx.x * blockDim.x + threadIdx.x;
    if (i < E) rank[i] = atomicAdd(&counts[dst[i]], 1);
}

__global__ __launch_bounds__(256)
void scan1_k(const int* __restrict__ counts, int* __restrict__ pre,
             int* __restrict__ bsum, int n) {
    __shared__ int sh[256];
    const int t = threadIdx.x;
    const int i = blockIdx.x * 256 + t;
    int v = (i < n) ? counts[i] : 0;
    sh[t] = v;
    __syncthreads();
    #pragma unroll
    for (int d = 1; d < 256; d <<= 1) {
        int x = (t >= d) ? sh[t - d] : 0;
        __syncthreads();
        sh[t] += x;
        __syncthreads();
    }
    if (i < n) pre[i] = sh[t] - v;
    if (t == 255) bsum[blockIdx.x] = sh[255];
}

// stage 2+3 fused: each block computes its offset = sum(bsum[0..bid)) inline
__global__ __launch_bounds__(256)
void scan3_k(const int* __restrict__ pre, const int* __restrict__ bsum,
             int* __restrict__ offsets, int n, int nb, int total) {
    __shared__ int sh[256];
    const int t = threadIdx.x;
    const int bid = blockIdx.x;
    sh[t] = (t < nb && t < bid) ? bsum[t] : 0;
    __syncthreads();
    #pragma unroll
    for (int d = 128; d > 0; d >>= 1) {
        if (t < d) sh[t] += sh[t + d];
        __syncthreads();
    }
    const int boff = sh[0];
    const int i = bid * 256 + t;
    if (i < n) offsets[i] = pre[i] + boff;
    if (i == 0) offsets[n] = total;
}

// ---------------------------------------------------------------------------
// Aggregate fp16 message rows (512 B), fp32 accumulate, fp16 out into
// hcat cols 256..511. Unroll-8: 8 independent row loads in flight per wave.
// (r12 lesson: slicing cut FETCH 175->35 MB but tripled VALU -> 126 us;
//  this row-gather form at ~54.5 us is the proven operating point.)
// ---------------------------------------------------------------------------
__global__ void agg_k(const u16* __restrict__ t, const int* __restrict__ offsets,
                      const int* __restrict__ sorted_src,
                      u16* __restrict__ out, int n) {
    const int node = blockIdx.x * (blockDim.x >> 6) + (threadIdx.x >> 6);
    const int lane = threadIdx.x & 63;
    if (node >= n) return;
    const int s0 = offsets[node], s1 = offsets[node + 1];

    float4 a0 = make_float4(0.f, 0.f, 0.f, 0.f);
    float4 a1 = a0, a2 = a0, a3 = a0;

    int i = s0;
    for (; i + 8 <= s1; i += 8) {
        int e0 = sorted_src[i];
        int e1 = sorted_src[i + 1];
        int e2 = sorted_src[i + 2];
        int e3 = sorted_src[i + 3];
        int e4 = sorted_src[i + 4];
        int e5 = sorted_src[i + 5];
        int e6 = sorted_src[i + 6];
        int e7 = sorted_src[i + 7];
        ushort4 v0 = *reinterpret_cast<const ushort4*>(t + (size_t)e0 * 256 + lane * 4);
        ushort4 v1 = *reinterpret_cast<const ushort4*>(t + (size_t)e1 * 256 + lane * 4);
        ushort4 v2 = *reinterpret_cast<const ushort4*>(t + (size_t)e2 * 256 + lane * 4);
        ushort4 v3 = *reinterpret_cast<const ushort4*>(t + (size_t)e3 * 256 + lane * 4);
        ushort4 v4 = *reinterpret_cast<const ushort4*>(t + (size_t)e4 * 256 + lane * 4);
        ushort4 v5 = *reinterpret_cast<const ushort4*>(t + (size_t)e5 * 256 + lane * 4);
        ushort4 v6 = *reinterpret_cast<const ushort4*>(t + (size_t)e6 * 256 + lane * 4);
        ushort4 v7 = *reinterpret_cast<const ushort4*>(t + (size_t)e7 * 256 + lane * 4);
        a0.x += h2f(v0.x); a0.y += h2f(v0.y); a0.z += h2f(v0.z); a0.w += h2f(v0.w);
        a1.x += h2f(v1.x); a1.y += h2f(v1.y); a1.z += h2f(v1.z); a1.w += h2f(v1.w);
        a2.x += h2f(v2.x); a2.y += h2f(v2.y); a2.z += h2f(v2.z); a2.w += h2f(v2.w);
        a3.x += h2f(v3.x); a3.y += h2f(v3.y); a3.z += h2f(v3.z); a3.w += h2f(v3.w);
        a0.x += h2f(v4.x); a0.y += h2f(v4.y); a0.z += h2f(v4.z); a0.w += h2f(v4.w);
        a1.x += h2f(v5.x); a1.y += h2f(v5.y); a1.z += h2f(v5.z); a1.w += h2f(v5.w);
        a2.x += h2f(v6.x); a2.y += h2f(v6.y); a2.z += h2f(v6.z); a2.w += h2f(v6.w);
        a3.x += h2f(v7.x); a3.y += h2f(v7.y); a3.z += h2f(v7.z); a3.w += h2f(v7.w);
    }
    for (; i + 4 <= s1; i += 4) {
        int e0 = sorted_src[i];
        int e1 = sorted_src[i + 1];
        int e2 = sorted_src[i + 2];
        int e3 = sorted_src[i + 3];
        ushort4 v0 = *reinterpret_cast<const ushort4*>(t + (size_t)e0 * 256 + lane * 4);
        ushort4 v1 = *reinterpret_cast<const ushort4*>(t + (size_t)e1 * 256 + lane * 4);
        ushort4 v2 = *reinterpret_cast<const ushort4*>(t + (size_t)e2 * 256 + lane * 4);
        ushort4 v3 = *reinterpret_cast<const ushort4*>(t + (size_t)e3 * 256 + lane * 4);
        a0.x += h2f(v0.x); a0.y += h2f(v0.y); a0.z += h2f(v0.z); a0.w += h2f(v0.w);
        a1.x += h2f(v1.x); a1.y += h2f(v1.y); a1.z += h2f(v1.z); a1.w += h2f(v1.w);
        a2.x += h2f(v2.x); a2.y += h2f(v2.y); a2.z += h2f(v2.z); a2.w += h2f(v2.w);
        a3.x += h2f(v3.x); a3.y += h2f(v3.y); a3.z += h2f(v3.z); a3.w += h2f(v3.w);
    }
    for (; i < s1; ++i) {
        int e0 = sorted_src[i];
        ushort4 v0 = *reinterpret_cast<const ushort4*>(t + (size_t)e0 * 256 + lane * 4);
        a0.x += h2f(v0.x); a0.y += h2f(v0.y); a0.z += h2f(v0.z); a0.w += h2f(v0.w);
    }
    float4 acc;
    acc.x = (a0.x + a1.x) + (a2.x + a3.x);
    acc.y = (a0.y + a1.y) + (a2.y + a3.y);
    acc.z = (a0.z + a1.z) + (a2.z + a3.z);
    acc.w = (a0.w + a1.w) + (a2.w + a3.w);

    ushort4 h4;
    h4.x = f2h(acc.x); h4.y = f2h(acc.y); h4.z = f2h(acc.z); h4.w = f2h(acc.w);
    *reinterpret_cast<ushort4*>(out + (size_t)node * 512 + 256 + (size_t)lane * 4) = h4;
}

// ---------------------------------------------------------------------------
extern "C" void kernel_launch(void* const* d_in, const int* in_sizes, int n_in,
                              void* d_out, int out_size, void* d_ws, size_t ws_size,
                              hipStream_t stream) {
    const float* x       = (const float*)d_in[0];
    const int*   edges   = (const int*)d_in[1];
    const float* pre_w1  = (const float*)d_in[2];
    const float* pre_b1  = (const float*)d_in[3];
    const float* pre_w2  = (const float*)d_in[4];
    const float* pre_b2  = (const float*)d_in[5];
    const float* conv_w  = (const float*)d_in[6];
    const float* conv_b  = (const float*)d_in[7];
    const float* post_w1 = (const float*)d_in[8];
    const float* post_b1 = (const float*)d_in[9];
    const float* post_w2 = (const float*)d_in[10];
    const float* post_b2 = (const float*)d_in[11];

    const int N = in_sizes[0] / 16;
    const int E = in_sizes[1] / 2;
    const int* src = edges;
    const int* dst = edges + E;

    const int Mp128 = (N + 127) & ~127;

    // workspace layout (~85 MB)
    u16*   hcat = (u16*)d_ws;                              // Mp128 x 512 fp16: [t0 | agg]
    u16*   tf16 = hcat + (size_t)Mp128 * 512;              // Mp128 x 256 fp16
    u16*   wcT  = tf16 + (size_t)Mp128 * 256;              // 256 x 256 fp16 (W2@Wc)^T
    u16*   zWT  = wcT + 256 * 256;                         // 256 x 512 fp16 [(W2@P1h)^T | P1a^T]
    u16*   p2T  = zWT + 256 * 512;                         // 16 x 256 fp16
    float* btc  = (float*)(p2T + 16 * 256);                // 256 f32
    float* bzc  = btc + 256;                               // 256 f32
    int* offsets = (int*)(bzc + 256);                      // N+1
    int* counts  = offsets + (N + 1);                      // N
    int* rank    = counts + N;                             // E
    int* sorted  = rank + E;                               // E
    int* pre     = sorted + E;                             // N
    int* bsum    = pre + N;                                // <=256

    const dim3 blk(256);
    const int nsb   = (N + 255) / 256;
    const int npre  = (N + 15) / 16;
    const int NT    = Mp128 / 128;
    const int nfill = (E + 511) / 512;

    // fused setup: weight prep + counts zeroing + pre-MLP layer 1
    setup_k<<<786 + nsb + npre, blk, 0, stream>>>(
        pre_w2, pre_b2, conv_w, conv_b, post_w1, post_b1, post_w2,
        x, pre_w1, pre_b1,
        wcT, btc, zWT, bzc, p2T, counts, hcat, nsb, N);

    // CSR by destination (rank trick: fill is atomic-free, fused with t-GEMM)
    hist_k<<<(E + 255) / 256, blk, 0, stream>>>(dst, E, counts, rank);
    scan1_k<<<nsb, blk, 0, stream>>>(counts, pre, bsum, N);
    scan3_k<<<nsb, blk, 0, stream>>>(pre, bsum, offsets, N, nsb, E);

    // t-GEMM (t = relu(t0 @ wcT + btc) -> tf16)  ∪  CSR fill (independent)
    gemmfill_k<<<NT + nfill, dim3(512), 0, stream>>>(
        hcat, 512, wcT, btc, tf16, 256, N, 256, NT,
        src, dst, rank, offsets, sorted, E);

    // aggregate fp16 rows -> hcat[:, 256:]
    agg_k<<<(N + 3) / 4, blk, 0, stream>>>(tf16, offsets, sorted, hcat, N);
    // z = relu([t0|agg] @ zWT + bzc); out = tanh(z @ p2 + b2)  (fused)
    mfmaz_k<<<Mp128 / 128, dim3(512), 0, stream>>>(hcat, 512, zWT, bzc,
                                                   p2T, post_b2, (float*)d_out, N, 512);
}